// Round 10
// baseline (133.024 us; speedup 1.0000x reference)
//
#include <hip/hip_runtime.h>
#include <math.h>

typedef __attribute__((ext_vector_type(8))) short bf16x8;
typedef __attribute__((ext_vector_type(4))) float f32x4;
typedef __attribute__((ext_vector_type(16))) float f32x16;
typedef __attribute__((ext_vector_type(4))) unsigned int uint32x4;
typedef __attribute__((ext_vector_type(2))) unsigned int uint32x2;
typedef unsigned short ushort_t;
typedef unsigned int uint_t;

typedef const void __attribute__((address_space(1)))* gas_ptr;
typedef void __attribute__((address_space(3)))* las_ptr;

namespace {

constexpr int S_  = 2048;
constexpr int D_  = 1024;
constexpr float CSC = 0.18033688011f;   // 0.125 * log2(e): score scale in log2 domain

__device__ inline ushort_t f2bf(float f) {
    uint_t u = __builtin_bit_cast(uint_t, f);
    u += 0x7FFFu + ((u >> 16) & 1u);
    return (ushort_t)(u >> 16);
}
__device__ inline uint_t cvtpk(float lo, float hi) {
    uint_t r;
    asm("v_cvt_pk_bf16_f32 %0, %1, %2" : "=v"(r) : "v"(lo), "v"(hi));
    return r;
}
// permlane32_swap: swaps D.hi-half-lanes with S.lo-half-lanes (verified R6).
__device__ inline void plswap(uint_t& d, uint_t& s) {
    uint32x2 r = __builtin_amdgcn_permlane32_swap(d, s, false, false);
    d = r[0];
    s = r[1];
}

// ---------------------------------------------------------------------------
// transpose + convert fp32 [R][C] -> bf16 [C][R], one 64x64 tile.
// ---------------------------------------------------------------------------
__device__ inline void tconv_body(const float* __restrict__ src,
                                  ushort_t* __restrict__ dst,
                                  int R, int C, int r0, int c0, int tid)
{
    __shared__ float Tl[64][65];
    #pragma unroll
    for (int l = 0; l < 4; ++l) {
        int i = tid + l * 256;
        int row = i >> 4, col = (i & 15) * 4;
        float4 v = *(const float4*)(src + (size_t)(r0 + row) * C + c0 + col);
        Tl[row][col] = v.x; Tl[row][col + 1] = v.y;
        Tl[row][col + 2] = v.z; Tl[row][col + 3] = v.w;
    }
    __syncthreads();
    #pragma unroll
    for (int l = 0; l < 4; ++l) {
        int i = tid + l * 256;
        int cc = i >> 4, rr = (i & 15) * 4;
        uint_t lo = (uint_t)f2bf(Tl[rr][cc])     | ((uint_t)f2bf(Tl[rr + 1][cc]) << 16);
        uint_t hi = (uint_t)f2bf(Tl[rr + 2][cc]) | ((uint_t)f2bf(Tl[rr + 3][cc]) << 16);
        *(uint2*)(dst + (size_t)(c0 + cc) * R + r0 + rr) = make_uint2(lo, hi);
    }
}

// ---------------------------------------------------------------------------
// fused prep: x->bf16 conv | rope table | QKV weight transposes | Wo transpose
// grid 3328 x 256.
// ---------------------------------------------------------------------------
__global__ __launch_bounds__(256)
void prep_kernel(const float* __restrict__ x,  const float* __restrict__ Wq,
                 const float* __restrict__ Wk, const float* __restrict__ Wv,
                 const float* __restrict__ Wo,
                 ushort_t* __restrict__ xb, ushort_t* __restrict__ Wt,
                 ushort_t* __restrict__ Wot, float* __restrict__ tbl)
{
    const int b = blockIdx.x, tid = threadIdx.x;
    if (b < 2048) {                                   // x fp32 -> bf16
        int i = b * 256 + tid;
        float4 a = ((const float4*)x)[i * 2];
        float4 c = ((const float4*)x)[i * 2 + 1];
        uint_t u0 = (uint_t)f2bf(a.x) | ((uint_t)f2bf(a.y) << 16);
        uint_t u1 = (uint_t)f2bf(a.z) | ((uint_t)f2bf(a.w) << 16);
        uint_t u2 = (uint_t)f2bf(c.x) | ((uint_t)f2bf(c.y) << 16);
        uint_t u3 = (uint_t)f2bf(c.z) | ((uint_t)f2bf(c.w) << 16);
        ((uint4*)xb)[i] = make_uint4(u0, u1, u2, u3);
    } else if (b < 2304) {                            // rope cos/sin table
        int i = (b - 2048) * 256 + tid;
        int s = i >> 5, p = i & 31;
        float inv = powf(10000.0f, -(float)p * (1.0f / 32.0f));
        float sn, cs;
        sincosf((float)s * inv, &sn, &cs);
        ((float2*)tbl)[i] = make_float2(cs, sn);
    } else if (b < 3072) {                            // Wq/Wk/Wv transpose (48 z x 16 r)
        int lin = b - 2304;
        int z = lin >> 4, rx = lin & 15;
        const float* src = (z < 16 ? Wq : z < 32 ? Wk : Wv) + (size_t)(z & 15) * 65536;
        tconv_body(src, Wt + (size_t)z * 65536, 1024, 64, rx * 64, 0, tid);
    } else {                                          // Wo transpose (16x16 tiles)
        int lin = b - 3072;
        tconv_body(Wo, Wot, 1024, 1024, (lin & 15) * 64, (lin >> 4) * 64, tid);
    }
}

// ---------------------------------------------------------------------------
// m97-style bf16 MFMA GEMM: C[M][N] = A[M][K] * Bt[N][K]^T
// MODE 0: QKV epilogue via LDS-transpose for coalesced 16B stores:
//         Q (pre-scaled CSC) and K RoPE'd in-epilogue; V stored transposed.
// MODE 1: fp32 epilogue -> Co[M][N]
// ---------------------------------------------------------------------------
template<int MODE>
__global__ __launch_bounds__(256)
void gemm_kernel(const ushort_t* __restrict__ A, const ushort_t* __restrict__ Bt,
                 ushort_t* __restrict__ Qo, ushort_t* __restrict__ Ko,
                 ushort_t* __restrict__ Vto, float* __restrict__ Co,
                 const float* __restrict__ tbl, int K)
{
    constexpr int SMEM_BYTES = (MODE == 0) ? 34816 : 16384;  // EP 128x136 u16 : staging
    __shared__ char smem[SMEM_BYTES];
    ushort_t* As = (ushort_t*)smem;          // 128x32 (8 KB)
    ushort_t* Bs = As + 4096;                // 128x32 (8 KB)

    const int tid  = threadIdx.x;
    const int w    = tid >> 6, lane = tid & 63;
    const int lq   = lane & 15, lk = lane >> 4;
    const int wr   = w >> 1, wc = w & 1;
    const int m0   = blockIdx.x * 128;
    const int n0   = blockIdx.y * 128;

    f32x4 acc[4][4] = {};

    for (int k0 = 0; k0 < K; k0 += 32) {
        #pragma unroll
        for (int i = 0; i < 2; ++i) {
            int c   = i * 256 + tid;
            int row = c >> 2, c4 = c & 3;
            const ushort_t* ga = A  + (size_t)(m0 + row) * K + k0 + c4 * 8;
            const ushort_t* gb = Bt + (size_t)(n0 + row) * K + k0 + c4 * 8;
            int base = (i * 256 + w * 64) * 16;
            __builtin_amdgcn_global_load_lds((gas_ptr)ga, (las_ptr)((char*)As + base), 16, 0, 0);
            __builtin_amdgcn_global_load_lds((gas_ptr)gb, (las_ptr)((char*)Bs + base), 16, 0, 0);
        }
        __syncthreads();

        bf16x8 a[4], b[4];
        #pragma unroll
        for (int m = 0; m < 4; ++m)
            a[m] = *(const bf16x8*)((const char*)As + (wr * 64 + m * 16 + lq) * 64 + lk * 16);
        #pragma unroll
        for (int n = 0; n < 4; ++n)
            b[n] = *(const bf16x8*)((const char*)Bs + (wc * 64 + n * 16 + lq) * 64 + lk * 16);
        #pragma unroll
        for (int m = 0; m < 4; ++m)
            #pragma unroll
            for (int n = 0; n < 4; ++n)
                acc[m][n] = __builtin_amdgcn_mfma_f32_16x16x32_bf16(a[m], b[n], acc[m][n], 0, 0, 0);
        __syncthreads();
    }

    if (MODE == 0) {
        const int sel = n0 >> 10;
        ushort_t* EP = (ushort_t*)smem;          // 128 rows x 136 (pad) u16
        const int h0 = (n0 & 1023) >> 6;         // head base for this 128-col tile
        if (sel < 2) {
            const float sc = (sel == 0) ? CSC : 1.0f;
            #pragma unroll
            for (int m = 0; m < 4; ++m) {
                #pragma unroll
                for (int r = 0; r < 4; ++r) {
                    int lrow = wr * 64 + m * 16 + lk * 4 + r;
                    int sG = (m0 + lrow) & 2047;
                    #pragma unroll
                    for (int n = 0; n < 4; ++n) {
                        int lcol = wc * 64 + n * 16 + lq;
                        int dk = lcol & 63;
                        float v = acc[m][n][r] * sc;
                        float2 cs = *(const float2*)(tbl + ((size_t)sG * 32 + (dk >> 1)) * 2);
                        float sp = __shfl_xor(v, 1);       // partner col dk^1
                        float rv = (dk & 1) ? (v * cs.x + sp * cs.y)
                                            : (v * cs.x - sp * cs.y);
                        EP[lrow * 136 + lcol] = f2bf(rv);
                    }
                }
            }
            __syncthreads();
            ushort_t* dst = (sel == 0) ? Qo : Ko;
            #pragma unroll
            for (int it = 0; it < 8; ++it) {
                int idx = it * 256 + tid;
                int row = idx >> 4, c16 = idx & 15;
                uint4 v = *(const uint4*)(EP + row * 136 + c16 * 8);
                int mg = m0 + row;
                int b_ = mg >> 11, s = mg & 2047;
                int h = h0 + (c16 >> 3);
                int dk0 = (c16 & 7) * 8;
                *(uint4*)(dst + (((size_t)b_ * 16 + h) * 2048 + s) * 64 + dk0) = v;
            }
        } else {
            // V: write col-major into EP -> transpose is free; coalesced stores
            #pragma unroll
            for (int m = 0; m < 4; ++m) {
                #pragma unroll
                for (int r = 0; r < 4; ++r) {
                    int lrow = wr * 64 + m * 16 + lk * 4 + r;
                    #pragma unroll
                    for (int n = 0; n < 4; ++n) {
                        int lcol = wc * 64 + n * 16 + lq;
                        EP[lcol * 136 + lrow] = f2bf(acc[m][n][r]);
                    }
                }
            }
            __syncthreads();
            #pragma unroll
            for (int it = 0; it < 8; ++it) {
                int idx = it * 256 + tid;
                int col = idx >> 4, c16 = idx & 15;
                uint4 v = *(const uint4*)(EP + col * 136 + c16 * 8);
                int h = h0 + (col >> 6);
                int dk = col & 63;
                int sb = m0 + c16 * 8;
                int b_ = sb >> 11, s = sb & 2047;
                *(uint4*)(Vto + (((size_t)b_ * 16 + h) * 64 + dk) * 2048 + s) = v;
            }
        }
    } else {
        #pragma unroll
        for (int m = 0; m < 4; ++m) {
            #pragma unroll
            for (int r = 0; r < 4; ++r) {
                int mg = m0 + wr * 64 + m * 16 + lk * 4 + r;
                #pragma unroll
                for (int n = 0; n < 4; ++n) {
                    int ng = n0 + wc * 64 + n * 16 + lq;
                    Co[(size_t)mg * D_ + ng] = acc[m][n][r];
                }
            }
        }
    }
}

// ---------------------------------------------------------------------------
// MFMA causal flash attention, swapped-QK^T 32x32x16 (R8-verified algebra).
// Block = 8 waves: wq = w&1 (q 32-half of 64-row q-tile), st = w>>1 (kv
// 32-quarter of 128-kv tile). 512 blocks = exactly 2/CU resident; each block
// processes TWO q-tiles {31-pr, pr} sequentially -> nt sum = 17 for every
// block (uniform makespan, no dispatch tail).
// ---------------------------------------------------------------------------
__global__ __launch_bounds__(512)
void attn_kernel(const ushort_t* __restrict__ Q, const ushort_t* __restrict__ Kg,
                 const ushort_t* __restrict__ Vt, ushort_t* __restrict__ O)
{
    __shared__ ushort_t Ks[2][128 * 64];   // [kv][dk], row stride 128 B
    __shared__ ushort_t Vs[2][64 * 128];   // [dk][kv], row stride 256 B

    const int bid = blockIdx.x;            // 0..511
    const int bh  = bid & 31;
    const int pr  = bid >> 5;              // 0..15

    const int tid = threadIdx.x;           // 0..511
    const int w = tid >> 6, lane = tid & 63;
    const int wq = w & 1, st = w >> 1;     // q-half, kv-quarter
    const int lq = lane & 31, hi = lane >> 5;
    const size_t bhBase = (size_t)bh * S_ * 64;

    // staging: 1024 x 16B slots per tensor, 2 slots/thread each; linear LDS
    // dest, pre-swizzled global source (slot ^ (row&7), rule 21c).
    const int slot0 = tid, slot1 = 512 + tid;
    const int rK0 = slot0 >> 3, rK1 = slot1 >> 3;
    const int rV0 = slot0 >> 4, rV1 = slot1 >> 4;
    const ushort_t* gk0 = Kg + bhBase + (size_t)rK0 * 64 + ((slot0 & 7) ^ (rK0 & 7)) * 8;
    const ushort_t* gk1 = Kg + bhBase + (size_t)rK1 * 64 + ((slot1 & 7) ^ (rK1 & 7)) * 8;
    const ushort_t* gv0 = Vt + bhBase + (size_t)rV0 * 2048 + ((slot0 & 15) ^ (rV0 & 7)) * 8;
    const ushort_t* gv1 = Vt + bhBase + (size_t)rV1 * 2048 + ((slot1 & 15) ^ (rV1 & 7)) * 8;

    auto stage = [&](int buf, int t) {
        const size_t ko = (size_t)t * 128 * 64;   // K advances 128 rows/tile
        const size_t vo = (size_t)t * 128;        // V advances 128 kv cols/tile
        __builtin_amdgcn_global_load_lds((gas_ptr)(gk0 + ko), (las_ptr)((char*)Ks[buf] + slot0 * 16), 16, 0, 0);
        __builtin_amdgcn_global_load_lds((gas_ptr)(gk1 + ko), (las_ptr)((char*)Ks[buf] + slot1 * 16), 16, 0, 0);
        __builtin_amdgcn_global_load_lds((gas_ptr)(gv0 + vo), (las_ptr)((char*)Vs[buf] + slot0 * 16), 16, 0, 0);
        __builtin_amdgcn_global_load_lds((gas_ptr)(gv1 + vo), (las_ptr)((char*)Vs[buf] + slot1 * 16), 16, 0, 0);
    };

    const int krow = st * 32 + lq;         // this wave's kv row in the 128-tile

    #pragma unroll 1
    for (int pass = 0; pass < 2; ++pass) {
        const int p    = pass ? pr : 31 - pr;
        const int nt   = (p >> 1) + 1;
        const int qrel = ((p & 1) << 1) + wq;

        // Q fragments (B-operand): lane holds Q[q][c*16 + hi*8 .. +8]
        bf16x8 qf[4];
        {
            const ushort_t* qp = Q + bhBase + (size_t)(p * 64 + wq * 32 + lq) * 64 + hi * 8;
            qf[0] = *(const bf16x8*)(qp);
            qf[1] = *(const bf16x8*)(qp + 16);
            qf[2] = *(const bf16x8*)(qp + 32);
            qf[3] = *(const bf16x8*)(qp + 48);
        }

        float m = -1e30f, l = 0.0f;
        f32x16 oacc[2] = {};

        if (pass) __syncthreads();         // merge-scratch reads done before restage

        stage(0, 0);

        for (int t = 0; t < nt; ++t) {
            const int cur = t & 1;
            if (t < nt - 1) {
                stage(cur ^ 1, t + 1);
                asm volatile("s_waitcnt vmcnt(4)" ::: "memory");   // drain current tile's 4
            } else {
                asm volatile("s_waitcnt vmcnt(0)" ::: "memory");
            }
            __builtin_amdgcn_s_barrier();
            asm volatile("" ::: "memory");

            const bool last = (t == nt - 1);
            if (!(last && st > qrel)) {    // fully-masked quarter: staging only
                // S^T[kv=32][q=32] = K-frag * Q-frag over k=64
                f32x16 sacc = {};
                #pragma unroll
                for (int c = 0; c < 4; ++c) {
                    int koff = krow * 128 + ((c * 32 + hi * 16) ^ ((krow & 7) << 4));
                    bf16x8 kf = *(const bf16x8*)((const char*)Ks[cur] + koff);
                    sacc = __builtin_amdgcn_mfma_f32_32x32x16_bf16(kf, qf[c], sacc, 0, 0, 0);
                }

                if (last && st == qrel) {  // triangular 32x32 sub-tile
                    #pragma unroll
                    for (int idx = 0; idx < 16; ++idx) {
                        int kvl = (idx & 3) + 8 * (idx >> 2) + 4 * hi;
                        if (kvl > lq) sacc[idx] = -1e30f;
                    }
                }

                float pm = fmaxf(sacc[0], sacc[1]);
                #pragma unroll
                for (int idx = 2; idx < 16; idx += 2)
                    pm = fmaxf(fmaxf(pm, sacc[idx]), sacc[idx + 1]);
                pm = fmaxf(pm, __shfl_xor(pm, 32));

                if (__any(pm > m + 11.5f)) {   // defer-max (log2 domain)
                    float mn = fmaxf(m, pm);
                    float al = exp2f(m - mn);
                    m = mn;
                    l *= al;
                    #pragma unroll
                    for (int idx = 0; idx < 16; ++idx) { oacc[0][idx] *= al; oacc[1][idx] *= al; }
                }

                float pv[16];
                #pragma unroll
                for (int idx = 0; idx < 16; ++idx) {
                    float v = exp2f(sacc[idx] - m);
                    pv[idx] = v;
                    l += v;
                }

                // PV: O^T[dk][q] += V^T-frag * P^T-frag; kv chunks of 16
                #pragma unroll
                for (int c2 = 0; c2 < 2; ++c2) {
                    uint_t w0 = cvtpk(pv[8 * c2 + 0], pv[8 * c2 + 1]);
                    uint_t w1 = cvtpk(pv[8 * c2 + 2], pv[8 * c2 + 3]);
                    uint_t w2 = cvtpk(pv[8 * c2 + 4], pv[8 * c2 + 5]);
                    uint_t w3 = cvtpk(pv[8 * c2 + 6], pv[8 * c2 + 7]);
                    plswap(w0, w2);
                    plswap(w1, w3);
                    uint32x4 pw; pw[0] = w0; pw[1] = w1; pw[2] = w2; pw[3] = w3;
                    bf16x8 pb = __builtin_bit_cast(bf16x8, pw);
                    #pragma unroll
                    for (int d2 = 0; d2 < 2; ++d2) {
                        int vrow = d2 * 32 + lq;   // dk row; V row stride = 16 slots
                        int vslot = (st * 4 + c2 * 2 + hi) ^ (vrow & 7);
                        bf16x8 vf = *(const bf16x8*)((const char*)Vs[cur] + vrow * 256 + vslot * 16);
                        oacc[d2] = __builtin_amdgcn_mfma_f32_32x32x16_bf16(vf, pb, oacc[d2], 0, 0, 0);
                    }
                }
            }
            asm volatile("" ::: "memory");
            __builtin_amdgcn_s_barrier();  // all reads of buf[cur] done
            asm volatile("" ::: "memory");
        }

        // combine own-row l across lane halves (kv sub-chunks)
        l += __shfl_xor(l, 32);

        __syncthreads();                   // LDS now dead -> reuse as merge scratch

        // scratch: st=1 -> Ks floats [0,4096); st=2 -> Ks [4096,8192);
        //          st=3 -> Vs [0,4096); m,l -> Vs [4096 + (st-1)*512 + rowi*2]
        float* ksf = (float*)Ks;
        float* vsf = (float*)Vs;
        const int rowi = wq * 64 + lane;   // 0..127
        if (st != 0) {
            float* dst = (st == 1) ? ksf : (st == 2) ? (ksf + 4096) : vsf;
            #pragma unroll
            for (int j = 0; j < 8; ++j) {
                f32x4 v4;
                v4[0] = oacc[j >> 2][(j & 3) * 4 + 0];
                v4[1] = oacc[j >> 2][(j & 3) * 4 + 1];
                v4[2] = oacc[j >> 2][(j & 3) * 4 + 2];
                v4[3] = oacc[j >> 2][(j & 3) * 4 + 3];
                *(f32x4*)(dst + rowi * 32 + ((j ^ (rowi & 7)) * 4)) = v4;
            }
            vsf[4096 + (st - 1) * 512 + rowi * 2]     = m;
            vsf[4096 + (st - 1) * 512 + rowi * 2 + 1] = l;
        }
        __syncthreads();
        if (st == 0) {
            float ms[3], ls[3];
            #pragma unroll
            for (int s2 = 0; s2 < 3; ++s2) {
                ms[s2] = vsf[4096 + s2 * 512 + rowi * 2];
                ls[s2] = vsf[4096 + s2 * 512 + rowi * 2 + 1];
            }
            float M = fmaxf(fmaxf(m, ms[0]), fmaxf(ms[1], ms[2]));
            float a0 = exp2f(m - M);
            float a1 = exp2f(ms[0] - M), a2 = exp2f(ms[1] - M), a3 = exp2f(ms[2] - M);
            float lt = a0 * l + a1 * ls[0] + a2 * ls[1] + a3 * ls[2];
            float inv = 1.0f / lt;
            const int b_ = bh >> 4, h = bh & 15;
            const int s = p * 64 + wq * 32 + lq;
            ushort_t* ob = O + ((size_t)b_ * 2048 + s) * 1024 + h * 64;
            #pragma unroll
            for (int j = 0; j < 8; ++j) {
                int soff = rowi * 32 + ((j ^ (rowi & 7)) * 4);
                f32x4 o1 = *(const f32x4*)(ksf + soff);
                f32x4 o2 = *(const f32x4*)(ksf + 4096 + soff);
                f32x4 o3 = *(const f32x4*)(vsf + soff);
                int d2 = j >> 2, base = (j & 3) * 4;
                float q0 = (a0 * oacc[d2][base + 0] + a1 * o1[0] + a2 * o2[0] + a3 * o3[0]) * inv;
                float q1 = (a0 * oacc[d2][base + 1] + a1 * o1[1] + a2 * o2[1] + a3 * o3[1]) * inv;
                float q2 = (a0 * oacc[d2][base + 2] + a1 * o1[2] + a2 * o2[2] + a3 * o3[2]) * inv;
                float q3 = (a0 * oacc[d2][base + 3] + a1 * o1[3] + a2 * o2[3] + a3 * o3[3]) * inv;
                uint2 pkv;
                pkv.x = cvtpk(q0, q1);
                pkv.y = cvtpk(q2, q3);
                *(uint2*)(ob + d2 * 32 + 8 * (j & 3) + 4 * hi) = pkv;
            }
        }
    }
}

} // anonymous namespace

extern "C" void kernel_launch(void* const* d_in, const int* in_sizes, int n_in,
                              void* d_out, int out_size, void* d_ws, size_t ws_size,
                              hipStream_t stream)
{
    const float* x  = (const float*)d_in[0];
    const float* Wq = (const float*)d_in[1];
    const float* Wk = (const float*)d_in[2];
    const float* Wv = (const float*)d_in[3];
    const float* Wo = (const float*)d_in[4];

    ushort_t* xb  = (ushort_t*)d_ws;              // [4096][1024]        4M elems
    ushort_t* Wt  = xb  + 4194304;                // [3072][1024] (B^T)  3M elems
    ushort_t* Wot = Wt  + 3145728;                // [1024][1024] (B^T)  1M elems
    ushort_t* Qb  = Wot + 1048576;                // [32][2048][64]      4M elems
    ushort_t* Kb  = Qb  + 4194304;                // [32][2048][64]      4M elems
    ushort_t* Vtb = Kb  + 4194304;                // [32][64][2048]      4M elems
    ushort_t* Ob  = Vtb + 4194304;                // [4096][1024]        4M elems
    float*    tbl = (float*)(Ob + 4194304);       // [2048][32][2] fp32  512 KB

    prep_kernel<<<3328, 256, 0, stream>>>(x, Wq, Wk, Wv, Wo, xb, Wt, Wot, tbl);

    gemm_kernel<0><<<dim3(32, 24), 256, 0, stream>>>(xb, Wt, Qb, Kb, Vtb, nullptr, tbl, 1024);

    attn_kernel<<<512, 512, 0, stream>>>(Qb, Kb, Vtb, Ob);

    gemm_kernel<1><<<dim3(32, 8), 256, 0, stream>>>(Ob, Wot, nullptr, nullptr, nullptr,
                                                    (float*)d_out, nullptr, 1024);
}

// Round 11
// 121.972 us; speedup vs baseline: 1.0906x; 1.0906x over previous
//
#include <hip/hip_runtime.h>
#include <math.h>

typedef __attribute__((ext_vector_type(8))) short bf16x8;
typedef __attribute__((ext_vector_type(4))) float f32x4;
typedef __attribute__((ext_vector_type(16))) float f32x16;
typedef __attribute__((ext_vector_type(4))) unsigned int uint32x4;
typedef __attribute__((ext_vector_type(2))) unsigned int uint32x2;
typedef unsigned short ushort_t;
typedef unsigned int uint_t;

typedef const void __attribute__((address_space(1)))* gas_ptr;
typedef void __attribute__((address_space(3)))* las_ptr;

namespace {

constexpr int S_  = 2048;
constexpr int D_  = 1024;
constexpr float CSC = 0.18033688011f;   // 0.125 * log2(e): score scale in log2 domain

__device__ inline ushort_t f2bf(float f) {
    uint_t u = __builtin_bit_cast(uint_t, f);
    u += 0x7FFFu + ((u >> 16) & 1u);
    return (ushort_t)(u >> 16);
}
__device__ inline uint_t cvtpk(float lo, float hi) {
    uint_t r;
    asm("v_cvt_pk_bf16_f32 %0, %1, %2" : "=v"(r) : "v"(lo), "v"(hi));
    return r;
}
// permlane32_swap: swaps D.hi-half-lanes with S.lo-half-lanes (verified R6).
__device__ inline void plswap(uint_t& d, uint_t& s) {
    uint32x2 r = __builtin_amdgcn_permlane32_swap(d, s, false, false);
    d = r[0];
    s = r[1];
}

// ---------------------------------------------------------------------------
// transpose + convert fp32 [R][C] -> bf16 [C][R], one 64x64 tile.
// ---------------------------------------------------------------------------
__device__ inline void tconv_body(const float* __restrict__ src,
                                  ushort_t* __restrict__ dst,
                                  int R, int C, int r0, int c0, int tid)
{
    __shared__ float Tl[64][65];
    #pragma unroll
    for (int l = 0; l < 4; ++l) {
        int i = tid + l * 256;
        int row = i >> 4, col = (i & 15) * 4;
        float4 v = *(const float4*)(src + (size_t)(r0 + row) * C + c0 + col);
        Tl[row][col] = v.x; Tl[row][col + 1] = v.y;
        Tl[row][col + 2] = v.z; Tl[row][col + 3] = v.w;
    }
    __syncthreads();
    #pragma unroll
    for (int l = 0; l < 4; ++l) {
        int i = tid + l * 256;
        int cc = i >> 4, rr = (i & 15) * 4;
        uint_t lo = (uint_t)f2bf(Tl[rr][cc])     | ((uint_t)f2bf(Tl[rr + 1][cc]) << 16);
        uint_t hi = (uint_t)f2bf(Tl[rr + 2][cc]) | ((uint_t)f2bf(Tl[rr + 3][cc]) << 16);
        *(uint2*)(dst + (size_t)(c0 + cc) * R + r0 + rr) = make_uint2(lo, hi);
    }
}

// ---------------------------------------------------------------------------
// fused prep: x->bf16 conv | rope table | QKV weight transposes | Wo transpose
// grid 3328 x 256.
// ---------------------------------------------------------------------------
__global__ __launch_bounds__(256)
void prep_kernel(const float* __restrict__ x,  const float* __restrict__ Wq,
                 const float* __restrict__ Wk, const float* __restrict__ Wv,
                 const float* __restrict__ Wo,
                 ushort_t* __restrict__ xb, ushort_t* __restrict__ Wt,
                 ushort_t* __restrict__ Wot, float* __restrict__ tbl)
{
    const int b = blockIdx.x, tid = threadIdx.x;
    if (b < 2048) {                                   // x fp32 -> bf16
        int i = b * 256 + tid;
        float4 a = ((const float4*)x)[i * 2];
        float4 c = ((const float4*)x)[i * 2 + 1];
        uint_t u0 = (uint_t)f2bf(a.x) | ((uint_t)f2bf(a.y) << 16);
        uint_t u1 = (uint_t)f2bf(a.z) | ((uint_t)f2bf(a.w) << 16);
        uint_t u2 = (uint_t)f2bf(c.x) | ((uint_t)f2bf(c.y) << 16);
        uint_t u3 = (uint_t)f2bf(c.z) | ((uint_t)f2bf(c.w) << 16);
        ((uint4*)xb)[i] = make_uint4(u0, u1, u2, u3);
    } else if (b < 2304) {                            // rope cos/sin table
        int i = (b - 2048) * 256 + tid;
        int s = i >> 5, p = i & 31;
        float inv = powf(10000.0f, -(float)p * (1.0f / 32.0f));
        float sn, cs;
        sincosf((float)s * inv, &sn, &cs);
        ((float2*)tbl)[i] = make_float2(cs, sn);
    } else if (b < 3072) {                            // Wq/Wk/Wv transpose (48 z x 16 r)
        int lin = b - 2304;
        int z = lin >> 4, rx = lin & 15;
        const float* src = (z < 16 ? Wq : z < 32 ? Wk : Wv) + (size_t)(z & 15) * 65536;
        tconv_body(src, Wt + (size_t)z * 65536, 1024, 64, rx * 64, 0, tid);
    } else {                                          // Wo transpose (16x16 tiles)
        int lin = b - 3072;
        tconv_body(Wo, Wot, 1024, 1024, (lin & 15) * 64, (lin >> 4) * 64, tid);
    }
}

// ---------------------------------------------------------------------------
// m97-style bf16 MFMA GEMM: C[M][N] = A[M][K] * Bt[N][K]^T
// MODE 0: QKV epilogue via LDS-transpose for coalesced 16B stores:
//         Q (pre-scaled CSC) and K RoPE'd in-epilogue; V stored transposed.
// MODE 1: fp32 epilogue via chunked LDS-transpose -> coalesced float4 stores.
// ---------------------------------------------------------------------------
template<int MODE>
__global__ __launch_bounds__(256)
void gemm_kernel(const ushort_t* __restrict__ A, const ushort_t* __restrict__ Bt,
                 ushort_t* __restrict__ Qo, ushort_t* __restrict__ Ko,
                 ushort_t* __restrict__ Vto, float* __restrict__ Co,
                 const float* __restrict__ tbl, int K)
{
    constexpr int SMEM_BYTES = (MODE == 0) ? 34816 : 16384;  // EP 128x136 u16 : staging/EPf
    __shared__ char smem[SMEM_BYTES];
    ushort_t* As = (ushort_t*)smem;          // 128x32 (8 KB)
    ushort_t* Bs = As + 4096;                // 128x32 (8 KB)

    const int tid  = threadIdx.x;
    const int w    = tid >> 6, lane = tid & 63;
    const int lq   = lane & 15, lk = lane >> 4;
    const int wr   = w >> 1, wc = w & 1;
    const int m0   = blockIdx.x * 128;
    const int n0   = blockIdx.y * 128;

    f32x4 acc[4][4] = {};

    for (int k0 = 0; k0 < K; k0 += 32) {
        #pragma unroll
        for (int i = 0; i < 2; ++i) {
            int c   = i * 256 + tid;
            int row = c >> 2, c4 = c & 3;
            const ushort_t* ga = A  + (size_t)(m0 + row) * K + k0 + c4 * 8;
            const ushort_t* gb = Bt + (size_t)(n0 + row) * K + k0 + c4 * 8;
            int base = (i * 256 + w * 64) * 16;
            __builtin_amdgcn_global_load_lds((gas_ptr)ga, (las_ptr)((char*)As + base), 16, 0, 0);
            __builtin_amdgcn_global_load_lds((gas_ptr)gb, (las_ptr)((char*)Bs + base), 16, 0, 0);
        }
        __syncthreads();

        bf16x8 a[4], b[4];
        #pragma unroll
        for (int m = 0; m < 4; ++m)
            a[m] = *(const bf16x8*)((const char*)As + (wr * 64 + m * 16 + lq) * 64 + lk * 16);
        #pragma unroll
        for (int n = 0; n < 4; ++n)
            b[n] = *(const bf16x8*)((const char*)Bs + (wc * 64 + n * 16 + lq) * 64 + lk * 16);
        #pragma unroll
        for (int m = 0; m < 4; ++m)
            #pragma unroll
            for (int n = 0; n < 4; ++n)
                acc[m][n] = __builtin_amdgcn_mfma_f32_16x16x32_bf16(a[m], b[n], acc[m][n], 0, 0, 0);
        __syncthreads();
    }

    if (MODE == 0) {
        const int sel = n0 >> 10;
        ushort_t* EP = (ushort_t*)smem;          // 128 rows x 136 (pad) u16
        const int h0 = (n0 & 1023) >> 6;         // head base for this 128-col tile
        if (sel < 2) {
            const float sc = (sel == 0) ? CSC : 1.0f;
            #pragma unroll
            for (int m = 0; m < 4; ++m) {
                #pragma unroll
                for (int r = 0; r < 4; ++r) {
                    int lrow = wr * 64 + m * 16 + lk * 4 + r;
                    int sG = (m0 + lrow) & 2047;
                    #pragma unroll
                    for (int n = 0; n < 4; ++n) {
                        int lcol = wc * 64 + n * 16 + lq;
                        int dk = lcol & 63;
                        float v = acc[m][n][r] * sc;
                        float2 cs = *(const float2*)(tbl + ((size_t)sG * 32 + (dk >> 1)) * 2);
                        float sp = __shfl_xor(v, 1);       // partner col dk^1
                        float rv = (dk & 1) ? (v * cs.x + sp * cs.y)
                                            : (v * cs.x - sp * cs.y);
                        EP[lrow * 136 + lcol] = f2bf(rv);
                    }
                }
            }
            __syncthreads();
            ushort_t* dst = (sel == 0) ? Qo : Ko;
            #pragma unroll
            for (int it = 0; it < 8; ++it) {
                int idx = it * 256 + tid;
                int row = idx >> 4, c16 = idx & 15;
                uint4 v = *(const uint4*)(EP + row * 136 + c16 * 8);
                int mg = m0 + row;
                int b_ = mg >> 11, s = mg & 2047;
                int h = h0 + (c16 >> 3);
                int dk0 = (c16 & 7) * 8;
                *(uint4*)(dst + (((size_t)b_ * 16 + h) * 2048 + s) * 64 + dk0) = v;
            }
        } else {
            // V: write col-major into EP -> transpose is free; coalesced stores
            #pragma unroll
            for (int m = 0; m < 4; ++m) {
                #pragma unroll
                for (int r = 0; r < 4; ++r) {
                    int lrow = wr * 64 + m * 16 + lk * 4 + r;
                    #pragma unroll
                    for (int n = 0; n < 4; ++n) {
                        int lcol = wc * 64 + n * 16 + lq;
                        EP[lcol * 136 + lrow] = f2bf(acc[m][n][r]);
                    }
                }
            }
            __syncthreads();
            #pragma unroll
            for (int it = 0; it < 8; ++it) {
                int idx = it * 256 + tid;
                int col = idx >> 4, c16 = idx & 15;
                uint4 v = *(const uint4*)(EP + col * 136 + c16 * 8);
                int h = h0 + (col >> 6);
                int dk = col & 63;
                int sb = m0 + c16 * 8;
                int b_ = sb >> 11, s = sb & 2047;
                *(uint4*)(Vto + (((size_t)b_ * 16 + h) * 64 + dk) * 2048 + s) = v;
            }
        }
    } else {
        // fp32 out: 4 chunks of 32 rows x 128 cols (16 KB) through LDS,
        // then fully-coalesced float4 stores (was: 64 scalar stores/thread).
        float* EPf = (float*)smem;
        #pragma unroll
        for (int m = 0; m < 4; ++m) {
            __syncthreads();                     // prior chunk reads / staging done
            #pragma unroll
            for (int r = 0; r < 4; ++r) {
                int lrow = wr * 16 + lk * 4 + r;           // 0..31 chunk-local
                #pragma unroll
                for (int n = 0; n < 4; ++n) {
                    int lcol = wc * 64 + n * 16 + lq;
                    EPf[lrow * 128 + lcol] = acc[m][n][r];
                }
            }
            __syncthreads();
            #pragma unroll
            for (int it = 0; it < 4; ++it) {
                int idx = it * 256 + tid;
                int rl = idx >> 5, c32 = idx & 31;
                float4 v = *(const float4*)(EPf + rl * 128 + c32 * 4);
                int grow = m0 + (rl >> 4) * 64 + m * 16 + (rl & 15);
                *(float4*)(Co + (size_t)grow * D_ + n0 + c32 * 4) = v;
            }
        }
    }
}

// ---------------------------------------------------------------------------
// MFMA causal flash attention, swapped-QK^T 32x32x16 (R8-measured config:
// 47.9 us). Block = 8 waves: wq = w&1 (q 32-half of 64-row q-tile),
// st = w>>1 (kv 32-quarter of 128-kv tile). grid 1024, longest q-tiles first.
// K [128 kv][64 dk], V^T [64 dk][128 kv] staged via global_load_lds with
// pre-swizzled source, double-buffered, counted vmcnt(4).
// Epilogue: 4-way (m,l,O) merge through the dead K/V LDS buffers.
// ---------------------------------------------------------------------------
__global__ __launch_bounds__(512)
void attn_kernel(const ushort_t* __restrict__ Q, const ushort_t* __restrict__ Kg,
                 const ushort_t* __restrict__ Vt, ushort_t* __restrict__ O)
{
    __shared__ ushort_t Ks[2][128 * 64];   // [kv][dk], row stride 128 B
    __shared__ ushort_t Vs[2][64 * 128];   // [dk][kv], row stride 256 B

    const int bid = blockIdx.x;
    const int p  = 31 - (bid >> 5);        // q-tile index, longest first
    const int bh = bid & 31;

    const int tid = threadIdx.x;           // 0..511
    const int w = tid >> 6, lane = tid & 63;
    const int wq = w & 1, st = w >> 1;     // q-half, kv-quarter
    const int lq = lane & 31, hi = lane >> 5;
    const size_t bhBase = (size_t)bh * S_ * 64;

    const int nt   = (p >> 1) + 1;         // kv 128-tiles to process
    const int qrel = ((p & 1) << 1) + wq;  // diagonal kv-quarter on last tile

    // Q fragments (B-operand): lane holds Q[q][c*16 + hi*8 .. +8]
    bf16x8 qf[4];
    {
        const ushort_t* qp = Q + bhBase + (size_t)(p * 64 + wq * 32 + lq) * 64 + hi * 8;
        qf[0] = *(const bf16x8*)(qp);
        qf[1] = *(const bf16x8*)(qp + 16);
        qf[2] = *(const bf16x8*)(qp + 32);
        qf[3] = *(const bf16x8*)(qp + 48);
    }

    // staging: 1024 x 16B slots per tensor, 2 slots/thread each; linear LDS
    // dest, pre-swizzled global source (slot ^ (row&7), rule 21c).
    const int slot0 = tid, slot1 = 512 + tid;
    const int rK0 = slot0 >> 3, rK1 = slot1 >> 3;
    const int rV0 = slot0 >> 4, rV1 = slot1 >> 4;
    const ushort_t* gk0 = Kg + bhBase + (size_t)rK0 * 64 + ((slot0 & 7) ^ (rK0 & 7)) * 8;
    const ushort_t* gk1 = Kg + bhBase + (size_t)rK1 * 64 + ((slot1 & 7) ^ (rK1 & 7)) * 8;
    const ushort_t* gv0 = Vt + bhBase + (size_t)rV0 * 2048 + ((slot0 & 15) ^ (rV0 & 7)) * 8;
    const ushort_t* gv1 = Vt + bhBase + (size_t)rV1 * 2048 + ((slot1 & 15) ^ (rV1 & 7)) * 8;

    auto stage = [&](int buf, int t) {
        const size_t ko = (size_t)t * 128 * 64;   // K advances 128 rows/tile
        const size_t vo = (size_t)t * 128;        // V advances 128 kv cols/tile
        __builtin_amdgcn_global_load_lds((gas_ptr)(gk0 + ko), (las_ptr)((char*)Ks[buf] + slot0 * 16), 16, 0, 0);
        __builtin_amdgcn_global_load_lds((gas_ptr)(gk1 + ko), (las_ptr)((char*)Ks[buf] + slot1 * 16), 16, 0, 0);
        __builtin_amdgcn_global_load_lds((gas_ptr)(gv0 + vo), (las_ptr)((char*)Vs[buf] + slot0 * 16), 16, 0, 0);
        __builtin_amdgcn_global_load_lds((gas_ptr)(gv1 + vo), (las_ptr)((char*)Vs[buf] + slot1 * 16), 16, 0, 0);
    };

    float m = -1e30f, l = 0.0f;
    f32x16 oacc[2] = {};

    const int krow = st * 32 + lq;         // this wave's kv row in the 128-tile

    stage(0, 0);

    for (int t = 0; t < nt; ++t) {
        const int cur = t & 1;
        if (t < nt - 1) {
            stage(cur ^ 1, t + 1);
            asm volatile("s_waitcnt vmcnt(4)" ::: "memory");   // drain current tile's 4
        } else {
            asm volatile("s_waitcnt vmcnt(0)" ::: "memory");
        }
        __builtin_amdgcn_s_barrier();
        asm volatile("" ::: "memory");

        const bool last = (t == nt - 1);
        if (!(last && st > qrel)) {        // fully-masked quarter: staging only
            // S^T[kv=32][q=32] = K-frag * Q-frag over k=64
            f32x16 sacc = {};
            #pragma unroll
            for (int c = 0; c < 4; ++c) {
                int koff = krow * 128 + ((c * 32 + hi * 16) ^ ((krow & 7) << 4));
                bf16x8 kf = *(const bf16x8*)((const char*)Ks[cur] + koff);
                sacc = __builtin_amdgcn_mfma_f32_32x32x16_bf16(kf, qf[c], sacc, 0, 0, 0);
            }

            if (last && st == qrel) {      // triangular 32x32 sub-tile
                #pragma unroll
                for (int idx = 0; idx < 16; ++idx) {
                    int kvl = (idx & 3) + 8 * (idx >> 2) + 4 * hi;
                    if (kvl > lq) sacc[idx] = -1e30f;
                }
            }

            float pm = fmaxf(sacc[0], sacc[1]);
            #pragma unroll
            for (int idx = 2; idx < 16; idx += 2)
                pm = fmaxf(fmaxf(pm, sacc[idx]), sacc[idx + 1]);
            pm = fmaxf(pm, __shfl_xor(pm, 32));

            if (__any(pm > m + 11.5f)) {   // defer-max (log2 domain)
                float mn = fmaxf(m, pm);
                float al = exp2f(m - mn);
                m = mn;
                l *= al;
                #pragma unroll
                for (int idx = 0; idx < 16; ++idx) { oacc[0][idx] *= al; oacc[1][idx] *= al; }
            }

            float pv[16];
            #pragma unroll
            for (int idx = 0; idx < 16; ++idx) {
                float v = exp2f(sacc[idx] - m);
                pv[idx] = v;
                l += v;
            }

            // PV: O^T[dk][q] += V^T-frag * P^T-frag; kv chunks of 16 in this quarter
            #pragma unroll
            for (int c2 = 0; c2 < 2; ++c2) {
                uint_t w0 = cvtpk(pv[8 * c2 + 0], pv[8 * c2 + 1]);
                uint_t w1 = cvtpk(pv[8 * c2 + 2], pv[8 * c2 + 3]);
                uint_t w2 = cvtpk(pv[8 * c2 + 4], pv[8 * c2 + 5]);
                uint_t w3 = cvtpk(pv[8 * c2 + 6], pv[8 * c2 + 7]);
                plswap(w0, w2);
                plswap(w1, w3);
                uint32x4 pw; pw[0] = w0; pw[1] = w1; pw[2] = w2; pw[3] = w3;
                bf16x8 pb = __builtin_bit_cast(bf16x8, pw);
                #pragma unroll
                for (int d2 = 0; d2 < 2; ++d2) {
                    int vrow = d2 * 32 + lq;   // dk row; V row stride = 16 slots
                    int vslot = (st * 4 + c2 * 2 + hi) ^ (vrow & 7);
                    bf16x8 vf = *(const bf16x8*)((const char*)Vs[cur] + vrow * 256 + vslot * 16);
                    oacc[d2] = __builtin_amdgcn_mfma_f32_32x32x16_bf16(vf, pb, oacc[d2], 0, 0, 0);
                }
            }
        }
        asm volatile("" ::: "memory");
        __builtin_amdgcn_s_barrier();      // all reads of buf[cur] done
        asm volatile("" ::: "memory");
    }

    // combine own-row l across lane halves (kv sub-chunks)
    l += __shfl_xor(l, 32);

    __syncthreads();                       // LDS now dead -> reuse as merge scratch

    // scratch: st=1 -> Ks floats [0,4096); st=2 -> Ks [4096,8192);
    //          st=3 -> Vs [0,4096); m,l -> Vs [4096 + (st-1)*512 + rowi*2]
    float* ksf = (float*)Ks;
    float* vsf = (float*)Vs;
    const int rowi = wq * 64 + lane;       // 0..127
    if (st != 0) {
        float* dst = (st == 1) ? ksf : (st == 2) ? (ksf + 4096) : vsf;
        #pragma unroll
        for (int j = 0; j < 8; ++j) {
            f32x4 v4;
            v4[0] = oacc[j >> 2][(j & 3) * 4 + 0];
            v4[1] = oacc[j >> 2][(j & 3) * 4 + 1];
            v4[2] = oacc[j >> 2][(j & 3) * 4 + 2];
            v4[3] = oacc[j >> 2][(j & 3) * 4 + 3];
            *(f32x4*)(dst + rowi * 32 + ((j ^ (rowi & 7)) * 4)) = v4;
        }
        vsf[4096 + (st - 1) * 512 + rowi * 2]     = m;
        vsf[4096 + (st - 1) * 512 + rowi * 2 + 1] = l;
    }
    __syncthreads();
    if (st == 0) {
        float ms[3], ls[3];
        #pragma unroll
        for (int s2 = 0; s2 < 3; ++s2) {
            ms[s2] = vsf[4096 + s2 * 512 + rowi * 2];
            ls[s2] = vsf[4096 + s2 * 512 + rowi * 2 + 1];
        }
        float M = fmaxf(fmaxf(m, ms[0]), fmaxf(ms[1], ms[2]));
        float a0 = exp2f(m - M);
        float a1 = exp2f(ms[0] - M), a2 = exp2f(ms[1] - M), a3 = exp2f(ms[2] - M);
        float lt = a0 * l + a1 * ls[0] + a2 * ls[1] + a3 * ls[2];
        float inv = 1.0f / lt;
        const int b_ = bh >> 4, h = bh & 15;
        const int s = p * 64 + wq * 32 + lq;
        ushort_t* ob = O + ((size_t)b_ * 2048 + s) * 1024 + h * 64;
        #pragma unroll
        for (int j = 0; j < 8; ++j) {
            int soff = rowi * 32 + ((j ^ (rowi & 7)) * 4);
            f32x4 o1 = *(const f32x4*)(ksf + soff);
            f32x4 o2 = *(const f32x4*)(ksf + 4096 + soff);
            f32x4 o3 = *(const f32x4*)(vsf + soff);
            int d2 = j >> 2, base = (j & 3) * 4;
            float q0 = (a0 * oacc[d2][base + 0] + a1 * o1[0] + a2 * o2[0] + a3 * o3[0]) * inv;
            float q1 = (a0 * oacc[d2][base + 1] + a1 * o1[1] + a2 * o2[1] + a3 * o3[1]) * inv;
            float q2 = (a0 * oacc[d2][base + 2] + a1 * o1[2] + a2 * o2[2] + a3 * o3[2]) * inv;
            float q3 = (a0 * oacc[d2][base + 3] + a1 * o1[3] + a2 * o2[3] + a3 * o3[3]) * inv;
            uint2 pkv;
            pkv.x = cvtpk(q0, q1);
            pkv.y = cvtpk(q2, q3);
            *(uint2*)(ob + d2 * 32 + 8 * (j & 3) + 4 * hi) = pkv;
        }
    }
}

} // anonymous namespace

extern "C" void kernel_launch(void* const* d_in, const int* in_sizes, int n_in,
                              void* d_out, int out_size, void* d_ws, size_t ws_size,
                              hipStream_t stream)
{
    const float* x  = (const float*)d_in[0];
    const float* Wq = (const float*)d_in[1];
    const float* Wk = (const float*)d_in[2];
    const float* Wv = (const float*)d_in[3];
    const float* Wo = (const float*)d_in[4];

    ushort_t* xb  = (ushort_t*)d_ws;              // [4096][1024]        4M elems
    ushort_t* Wt  = xb  + 4194304;                // [3072][1024] (B^T)  3M elems
    ushort_t* Wot = Wt  + 3145728;                // [1024][1024] (B^T)  1M elems
    ushort_t* Qb  = Wot + 1048576;                // [32][2048][64]      4M elems
    ushort_t* Kb  = Qb  + 4194304;                // [32][2048][64]      4M elems
    ushort_t* Vtb = Kb  + 4194304;                // [32][64][2048]      4M elems
    ushort_t* Ob  = Vtb + 4194304;                // [4096][1024]        4M elems
    float*    tbl = (float*)(Ob + 4194304);       // [2048][32][2] fp32  512 KB

    prep_kernel<<<3328, 256, 0, stream>>>(x, Wq, Wk, Wv, Wo, xb, Wt, Wot, tbl);

    gemm_kernel<0><<<dim3(32, 24), 256, 0, stream>>>(xb, Wt, Qb, Kb, Vtb, nullptr, tbl, 1024);

    attn_kernel<<<1024, 512, 0, stream>>>(Qb, Kb, Vtb, Ob);

    gemm_kernel<1><<<dim3(32, 8), 256, 0, stream>>>(Ob, Wot, nullptr, nullptr, nullptr,
                                                    (float*)d_out, nullptr, 1024);
}